// Round 6
// baseline (229.636 us; speedup 1.0000x reference)
//
#include <hip/hip_runtime.h>
#include <hip/hip_bf16.h>

typedef __attribute__((ext_vector_type(4))) float f32x4;
typedef __attribute__((ext_vector_type(8))) short bf16x8;
typedef __attribute__((ext_vector_type(8))) unsigned short u16x8;
typedef __attribute__((ext_vector_type(4))) unsigned int u32x4;

#define HH 112
#define WW 112
#define CIN 64
#define COUT 128
#define HOUT 110
#define WOUT 110
#define MTOT 387200
#define NWG 3025  // 387200 / 128
#define NXCD 8

__device__ __forceinline__ unsigned short f2bf(float f) {
  unsigned int x = __float_as_uint(f);
  x += 0x7fffu + ((x >> 16) & 1u);
  return (unsigned short)(x >> 16);
}

// packed fp32 pair -> bf16 pair (v_cvt_pk_bf16_f32)
__device__ __forceinline__ unsigned int cvt2(float lo, float hi) {
  union { __hip_bfloat162 h; unsigned int u; } cv;
  cv.h = __float22bfloat162_rn(float2{lo, hi});
  return cv.u;
}

// Prepack kernels (3,3,64,128) fp32 HWIO -> bt in the SWIZZLED LDS-image
// layout: bt[tap*8192 + co*64 + e] = bf16(B[tap][ci][co]), ci = ((e*2)^((co&7)<<4))>>1.
// Staging into LDS is then a pure linear copy; readers use the swizzled offsets.
__global__ void prepack_b_kernel(const float* __restrict__ kern,
                                 unsigned short* __restrict__ bt) {
  int idx = blockIdx.x * 256 + threadIdx.x;
  if (idx >= 9 * 8192) return;
  int tap = idx >> 13;
  int rem = idx & 8191;
  int co = rem >> 6;
  int e = rem & 63;
  int ci = ((e * 2) ^ ((co & 7) << 4)) >> 1;
  bt[idx] = f2bf(kern[(tap * 64 + ci) * COUT + co]);
}

template <bool PREPACK>
__global__ __launch_bounds__(512, 4)
void conv_mfma_kernel(const float* __restrict__ x,
                      const void* __restrict__ bsrc,
                      const float* __restrict__ bias,
                      float* __restrict__ out) {
  // Only B lives in LDS (double-buffered, swizzled image): 2 x 16 KB.
  // A fragments load DIRECTLY from global into registers (L1/L2-resident slab).
  __shared__ __align__(16) unsigned short Bs[2][8192];

  const int tid = threadIdx.x;

  // ---- bijective XCD-chunked remap (m204)
  const int bid = blockIdx.x;
  const int q = NWG / NXCD, r = NWG % NXCD;
  const int xcd = bid % NXCD, i8 = bid / NXCD;
  const int wg = (xcd < r ? xcd * (q + 1) : r * (q + 1) + (xcd - r) * q) + i8;
  const int m0 = wg * 128;

  // ---- compute config: 8 waves = 4(m) x 2(n); wave tile 32x64 = 2x4 frags
  const int lane = tid & 63;
  const int wid = tid >> 6;
  const int wm = wid >> 1;
  const int wn = wid & 1;
  const int l16 = lane & 15;
  const int lk = lane >> 4;
  const int swzR = (l16 & 7) << 4;

  // ---- A-direct: per-lane base pointers for this lane's 2 fragment rows.
  // Frag layout (16x16x32): lane (l16,lk) holds row l16, k = lk*8..+8;
  // here k indexes input channels (contiguous in NHWC) -> 32 B contiguous/lane.
  const float* pa[2];
#pragma unroll
  for (int f = 0; f < 2; ++f) {
    const int mrow = m0 + wm * 32 + f * 16 + l16;
    const int wo = mrow % WOUT;
    const int t = mrow / WOUT;
    const int ho = t % HOUT;
    const int bb = t / HOUT;
    pa[f] = x + (((bb * HH) + ho) * WW + wo) * CIN + lk * 8;
  }

  const unsigned short* btp = (const unsigned short*)bsrc;
  // fallback direct-B staging coords
  const int bci = tid >> 3;
  const int bco = (tid & 7) * 16;

  const int broff0 = (wn * 64 + 0 + l16) * 64;
  const int broff1 = (wn * 64 + 16 + l16) * 64;
  const int broff2 = (wn * 64 + 32 + l16) * 64;
  const int broff3 = (wn * 64 + 48 + l16) * 64;

  f32x4 acc[2][4];
#pragma unroll
  for (int i = 0; i < 2; ++i)
#pragma unroll
    for (int j = 0; j < 4; ++j)
      acc[i][j] = (f32x4){0.f, 0.f, 0.f, 0.f};

  // A prefetch registers: [frag][kstep][half-16B]
  f32x4 p[2][2][2];
  u16x8 bq0, bq1;

  // ---- prologue: A tap-0 loads; B tap-0 stage into Bs[0]
#pragma unroll
  for (int f = 0; f < 2; ++f)
#pragma unroll
    for (int ks = 0; ks < 2; ++ks)
#pragma unroll
      for (int h = 0; h < 2; ++h)
        p[f][ks][h] = *(const f32x4*)(pa[f] + ks * 32 + h * 4);
  if constexpr (PREPACK) {
    const u16x8* s = (const u16x8*)(btp + tid * 16);
    *(u16x8*)(Bs[0] + tid * 16) = s[0];
    *(u16x8*)(Bs[0] + tid * 16 + 8) = s[1];
  } else {
    const float* kern = (const float*)bsrc;
    const float* kslab = kern + bci * COUT + bco;
#pragma unroll
    for (int j = 0; j < 16; ++j) {
      int c = bco + j;
      Bs[0][c * 64 + (((bci * 2) ^ ((c & 7) << 4)) >> 1)] = f2bf(kslab[j]);
    }
  }

#pragma unroll
  for (int kk = 0; kk < 9; ++kk) {
    const int cur = kk & 1;
    const int nxt = cur ^ 1;

    __syncthreads();  // Bs[cur] staged; prev readers of Bs[nxt] done; A regs landed

    // ---- convert this tap's prefetched A to bf16 fragments (frees p regs)
    bf16x8 af[2][2];
#pragma unroll
    for (int f = 0; f < 2; ++f)
#pragma unroll
      for (int ks = 0; ks < 2; ++ks) {
        union { u32x4 u; bf16x8 b; } cv;
        cv.u[0] = cvt2(p[f][ks][0][0], p[f][ks][0][1]);
        cv.u[1] = cvt2(p[f][ks][0][2], p[f][ks][0][3]);
        cv.u[2] = cvt2(p[f][ks][1][0], p[f][ks][1][1]);
        cv.u[3] = cvt2(p[f][ks][1][2], p[f][ks][1][3]);
        af[f][ks] = cv.b;
      }

    // ---- issue next tap's A loads (regs) + B slab loads (regs)
    if (kk < 8) {
      const int kn = kk + 1;
      const int kh2 = kn / 3;
      const int kw2 = kn - kh2 * 3;
      const int off = (kh2 * WW + kw2) * CIN;
#pragma unroll
      for (int f = 0; f < 2; ++f)
#pragma unroll
        for (int ks = 0; ks < 2; ++ks)
#pragma unroll
          for (int h = 0; h < 2; ++h)
            p[f][ks][h] = *(const f32x4*)(pa[f] + off + ks * 32 + h * 4);
      if constexpr (PREPACK) {
        const u16x8* s = (const u16x8*)(btp + kn * 8192 + tid * 16);
        bq0 = s[0];
        bq1 = s[1];
      }
    }

    // ---- compute from Bs[cur]: 2 k-steps of 32, 8 MFMA each
    const unsigned short* Bc = Bs[cur];
#pragma unroll
    for (int ks = 0; ks < 2; ++ks) {
      const int cbs = ((ks * 64 + lk * 16) ^ swzR) >> 1;
      bf16x8 b0 = *(const bf16x8*)(Bc + broff0 + cbs);
      bf16x8 b1 = *(const bf16x8*)(Bc + broff1 + cbs);
      bf16x8 b2 = *(const bf16x8*)(Bc + broff2 + cbs);
      bf16x8 b3 = *(const bf16x8*)(Bc + broff3 + cbs);
      acc[0][0] = __builtin_amdgcn_mfma_f32_16x16x32_bf16(af[0][ks], b0, acc[0][0], 0, 0, 0);
      acc[0][1] = __builtin_amdgcn_mfma_f32_16x16x32_bf16(af[0][ks], b1, acc[0][1], 0, 0, 0);
      acc[0][2] = __builtin_amdgcn_mfma_f32_16x16x32_bf16(af[0][ks], b2, acc[0][2], 0, 0, 0);
      acc[0][3] = __builtin_amdgcn_mfma_f32_16x16x32_bf16(af[0][ks], b3, acc[0][3], 0, 0, 0);
      acc[1][0] = __builtin_amdgcn_mfma_f32_16x16x32_bf16(af[1][ks], b0, acc[1][0], 0, 0, 0);
      acc[1][1] = __builtin_amdgcn_mfma_f32_16x16x32_bf16(af[1][ks], b1, acc[1][1], 0, 0, 0);
      acc[1][2] = __builtin_amdgcn_mfma_f32_16x16x32_bf16(af[1][ks], b2, acc[1][2], 0, 0, 0);
      acc[1][3] = __builtin_amdgcn_mfma_f32_16x16x32_bf16(af[1][ks], b3, acc[1][3], 0, 0, 0);
    }

    // ---- stage B(kk+1) into Bs[nxt]: pure linear copy (pre-swizzled source),
    //      stride-1 b128 writes (conflict-free); R5-proven placement.
    if (kk < 8) {
      if constexpr (PREPACK) {
        *(u16x8*)(Bs[nxt] + tid * 16) = bq0;
        *(u16x8*)(Bs[nxt] + tid * 16 + 8) = bq1;
      } else {
        const float* kern = (const float*)bsrc;
        const float* kslab = kern + ((kk + 1) * 64 + bci) * COUT + bco;
#pragma unroll
        for (int j = 0; j < 16; ++j) {
          int c = bco + j;
          Bs[nxt][c * 64 + (((bci * 2) ^ ((c & 7) << 4)) >> 1)] = f2bf(kslab[j]);
        }
      }
    }
  }

  // ---- epilogue: bias + relu, C/D layout col=lane&15, row=(lane>>4)*4+reg
  const int ncol = wn * 64 + l16;
  const float bv0 = bias[ncol + 0];
  const float bv1 = bias[ncol + 16];
  const float bv2 = bias[ncol + 32];
  const float bv3 = bias[ncol + 48];
  const int mrow0 = m0 + wm * 32 + lk * 4;
#pragma unroll
  for (int mf = 0; mf < 2; ++mf) {
#pragma unroll
    for (int j = 0; j < 4; ++j) {
      const int row = mrow0 + mf * 16 + j;
      float* orow = out + (size_t)row * COUT + ncol;
      orow[0]  = fmaxf(acc[mf][0][j] + bv0, 0.f);
      orow[16] = fmaxf(acc[mf][1][j] + bv1, 0.f);
      orow[32] = fmaxf(acc[mf][2][j] + bv2, 0.f);
      orow[48] = fmaxf(acc[mf][3][j] + bv3, 0.f);
    }
  }
}

extern "C" void kernel_launch(void* const* d_in, const int* in_sizes, int n_in,
                              void* d_out, int out_size, void* d_ws, size_t ws_size,
                              hipStream_t stream) {
  const float* x = (const float*)d_in[0];
  const float* kern = (const float*)d_in[1];
  const float* bias = (const float*)d_in[2];
  float* out = (float*)d_out;

  const size_t bt_bytes = 9 * 8192 * sizeof(unsigned short);
  if (d_ws != nullptr && ws_size >= bt_bytes) {
    unsigned short* bt = (unsigned short*)d_ws;
    prepack_b_kernel<<<288, 256, 0, stream>>>(kern, bt);
    conv_mfma_kernel<true><<<NWG, 512, 0, stream>>>(x, (const void*)bt, bias, out);
  } else {
    conv_mfma_kernel<false><<<NWG, 512, 0, stream>>>(x, (const void*)kern, bias, out);
  }
}

// Round 7
// 174.671 us; speedup vs baseline: 1.3147x; 1.3147x over previous
//
#include <hip/hip_runtime.h>
#include <hip/hip_bf16.h>

typedef __attribute__((ext_vector_type(4))) float f32x4;
typedef __attribute__((ext_vector_type(16))) float f32x16;
typedef __attribute__((ext_vector_type(8))) short bf16x8;
typedef __attribute__((ext_vector_type(8))) unsigned short u16x8;
typedef __attribute__((ext_vector_type(4))) unsigned int u32x4;

#define HH 112
#define WW 112
#define CIN 64
#define COUT 128
#define HOUT 110
#define WOUT 110
#define MTOT 387200
#define NWG 3025  // 387200 / 128
#define NXCD 8

__device__ __forceinline__ unsigned short f2bf(float f) {
  unsigned int x = __float_as_uint(f);
  x += 0x7fffu + ((x >> 16) & 1u);
  return (unsigned short)(x >> 16);
}

// packed fp32 pair -> bf16 pair (v_cvt_pk_bf16_f32)
__device__ __forceinline__ unsigned int cvt2(float lo, float hi) {
  union { __hip_bfloat162 h; unsigned int u; } cv;
  cv.h = __float22bfloat162_rn(float2{lo, hi});
  return cv.u;
}

// Prepack kernels (3,3,64,128) fp32 HWIO -> Bt[co][k] bf16, k = (kh*3+kw)*64+ci
__global__ void prepack_b_kernel(const float* __restrict__ kern,
                                 unsigned short* __restrict__ bt) {
  int idx = blockIdx.x * 256 + threadIdx.x;
  if (idx >= 576 * COUT) return;
  int co = idx / 576;
  int k = idx - co * 576;
  bt[idx] = f2bf(kern[k * COUT + co]);
}

template <bool PREPACK>
__global__ __launch_bounds__(256, 3)
void conv_mfma_kernel(const float* __restrict__ x,
                      const void* __restrict__ bsrc,
                      const float* __restrict__ bias,
                      float* __restrict__ out) {
  // Single-buffered swizzled LDS (32 KB) -> 3 blocks/CU; 3 independent
  // barrier groups per CU provide the cross-block overlap R4/R6 lacked.
  __shared__ __align__(16) unsigned short As[128 * 64];
  __shared__ __align__(16) unsigned short Bs[128 * 64];

  const int tid = threadIdx.x;

  // ---- bijective XCD-chunked remap (m204)
  const int bid = blockIdx.x;
  const int q = NWG / NXCD, r = NWG % NXCD;
  const int xcd = bid % NXCD, i8 = bid / NXCD;
  const int wg = (xcd < r ? xcd * (q + 1) : r * (q + 1) + (xcd - r) * q) + i8;
  const int m0 = wg * 128;

  // ---- staging config: A: thread -> (row sr 0..127, half sc 0..1 of 32 ch)
  //      B reuses the same (sr=co, sc=k-half) decomposition and offsets.
  const int sr = tid >> 1;
  const int sc = tid & 1;
  const int m = m0 + sr;
  const int wo = m % WOUT;
  const int t1 = m / WOUT;
  const int ho = t1 % HOUT;
  const int b = t1 / HOUT;
  const float* xrow = x + (((b * HH) + ho) * WW + wo) * CIN + sc * 32;
  const int swzS = (sr & 7) << 4;
  int awo[4];
#pragma unroll
  for (int i = 0; i < 4; ++i)
    awo[i] = sr * 64 + (((sc * 64 + i * 16) ^ swzS) >> 1);

  const unsigned short* btrow = nullptr;
  if constexpr (PREPACK) {
    btrow = (const unsigned short*)bsrc + sr * 576 + sc * 32;
  }
  // fallback direct-B staging coords (no-ws path only)
  const int fci = tid >> 2;
  const int fco = (tid & 3) * 32;

  // ---- compute config: 4 waves = 2(m) x 2(n); wave tile 64x64 = 2x2 frags
  //      of 32x32x16. A-frag: lane holds row=l31, k=hi*8+e; B-frag: col=l31.
  const int lane = tid & 63;
  const int wid = tid >> 6;
  const int wm = wid >> 1;
  const int wn = wid & 1;
  const int l31 = lane & 31;
  const int hi = lane >> 5;
  const int hi16 = hi * 16;
  const int swzC = (l31 & 7) << 4;

  const int arow0 = (wm * 64 + 0 + l31) * 64;
  const int arow1 = (wm * 64 + 32 + l31) * 64;
  const int bcol0 = (wn * 64 + 0 + l31) * 64;
  const int bcol1 = (wn * 64 + 32 + l31) * 64;

  f32x16 acc00 = {};
  f32x16 acc01 = {};
  f32x16 acc10 = {};
  f32x16 acc11 = {};

#pragma unroll
  for (int kk = 0; kk < 9; ++kk) {
    const int kh = kk / 3;
    const int kw = kk - kh * 3;

    __syncthreads();  // all readers of tap kk-1 done (WAR)

    // ---- stage A: x[b, ho+kh, wo+kw, sc*32 .. +32] -> As (bf16, swizzled)
    {
      const float* src = xrow + (kh * WW + kw) * CIN;
      f32x4 f0 = *(const f32x4*)(src + 0);
      f32x4 f1 = *(const f32x4*)(src + 4);
      f32x4 f2 = *(const f32x4*)(src + 8);
      f32x4 f3 = *(const f32x4*)(src + 12);
      f32x4 f4 = *(const f32x4*)(src + 16);
      f32x4 f5 = *(const f32x4*)(src + 20);
      f32x4 f6 = *(const f32x4*)(src + 24);
      f32x4 f7 = *(const f32x4*)(src + 28);
      u32x4 v0, v1, v2, v3;
      v0[0] = cvt2(f0[0], f0[1]); v0[1] = cvt2(f0[2], f0[3]);
      v0[2] = cvt2(f1[0], f1[1]); v0[3] = cvt2(f1[2], f1[3]);
      v1[0] = cvt2(f2[0], f2[1]); v1[1] = cvt2(f2[2], f2[3]);
      v1[2] = cvt2(f3[0], f3[1]); v1[3] = cvt2(f3[2], f3[3]);
      v2[0] = cvt2(f4[0], f4[1]); v2[1] = cvt2(f4[2], f4[3]);
      v2[2] = cvt2(f5[0], f5[1]); v2[3] = cvt2(f5[2], f5[3]);
      v3[0] = cvt2(f6[0], f6[1]); v3[1] = cvt2(f6[2], f6[3]);
      v3[2] = cvt2(f7[0], f7[1]); v3[3] = cvt2(f7[2], f7[3]);
      *(u32x4*)(As + awo[0]) = v0;
      *(u32x4*)(As + awo[1]) = v1;
      *(u32x4*)(As + awo[2]) = v2;
      *(u32x4*)(As + awo[3]) = v3;
    }

    // ---- stage B: Bs[co][k] (bf16, swizzled; same offset pattern as A)
    if constexpr (PREPACK) {
      const u16x8* s = (const u16x8*)(btrow + kk * 64);
      *(u16x8*)(Bs + awo[0]) = s[0];
      *(u16x8*)(Bs + awo[1]) = s[1];
      *(u16x8*)(Bs + awo[2]) = s[2];
      *(u16x8*)(Bs + awo[3]) = s[3];
    } else {
      const float* kern = (const float*)bsrc;
      const float* kslab = kern + (kk * 64 + fci) * COUT + fco;
#pragma unroll
      for (int j = 0; j < 32; ++j) {
        int c = fco + j;
        Bs[c * 64 + (((fci * 2) ^ ((c & 7) << 4)) >> 1)] = f2bf(kslab[j]);
      }
    }

    __syncthreads();  // tap kk staged

    // ---- compute: 4 k-steps of 16, 4 MFMA(32x32x16) each
#pragma unroll
    for (int ks = 0; ks < 4; ++ks) {
      const int coff = ((ks * 32 + hi16) ^ swzC) >> 1;
      bf16x8 a0 = *(const bf16x8*)(As + arow0 + coff);
      bf16x8 a1 = *(const bf16x8*)(As + arow1 + coff);
      bf16x8 b0 = *(const bf16x8*)(Bs + bcol0 + coff);
      bf16x8 b1 = *(const bf16x8*)(Bs + bcol1 + coff);
      acc00 = __builtin_amdgcn_mfma_f32_32x32x16_bf16(a0, b0, acc00, 0, 0, 0);
      acc01 = __builtin_amdgcn_mfma_f32_32x32x16_bf16(a0, b1, acc01, 0, 0, 0);
      acc10 = __builtin_amdgcn_mfma_f32_32x32x16_bf16(a1, b0, acc10, 0, 0, 0);
      acc11 = __builtin_amdgcn_mfma_f32_32x32x16_bf16(a1, b1, acc11, 0, 0, 0);
    }
  }

  // ---- epilogue: bias + relu.
  // C/D 32x32 layout: col = lane&31, row = (reg&3) + 8*(reg>>2) + 4*(lane>>5).
  const int col0 = wn * 64 + l31;
  const float bv0 = bias[col0];
  const float bv1 = bias[col0 + 32];
  const int rbase = m0 + wm * 64 + hi * 4;
#pragma unroll
  for (int qd = 0; qd < 4; ++qd) {
#pragma unroll
    for (int j = 0; j < 4; ++j) {
      const int rloc = j + qd * 8;
      const int e = qd * 4 + j;
      {
        float* o = out + (size_t)(rbase + rloc) * COUT + col0;
        o[0]  = fmaxf(acc00[e] + bv0, 0.f);
        o[32] = fmaxf(acc01[e] + bv1, 0.f);
      }
      {
        float* o = out + (size_t)(rbase + 32 + rloc) * COUT + col0;
        o[0]  = fmaxf(acc10[e] + bv0, 0.f);
        o[32] = fmaxf(acc11[e] + bv1, 0.f);
      }
    }
  }
}

extern "C" void kernel_launch(void* const* d_in, const int* in_sizes, int n_in,
                              void* d_out, int out_size, void* d_ws, size_t ws_size,
                              hipStream_t stream) {
  const float* x = (const float*)d_in[0];
  const float* kern = (const float*)d_in[1];
  const float* bias = (const float*)d_in[2];
  float* out = (float*)d_out;

  const size_t bt_bytes = 576 * COUT * sizeof(unsigned short);
  if (d_ws != nullptr && ws_size >= bt_bytes) {
    unsigned short* bt = (unsigned short*)d_ws;
    prepack_b_kernel<<<288, 256, 0, stream>>>(kern, bt);
    conv_mfma_kernel<true><<<NWG, 256, 0, stream>>>(x, (const void*)bt, bias, out);
  } else {
    conv_mfma_kernel<false><<<NWG, 256, 0, stream>>>(x, (const void*)kern, bias, out);
  }
}

// Round 8
// 110.079 us; speedup vs baseline: 2.0861x; 1.5868x over previous
//
#include <hip/hip_runtime.h>
#include <hip/hip_bf16.h>

typedef __attribute__((ext_vector_type(4))) float f32x4;
typedef __attribute__((ext_vector_type(8))) short bf16x8;
typedef __attribute__((ext_vector_type(8))) unsigned short u16x8;
typedef __attribute__((ext_vector_type(4))) unsigned int u32x4;

#define HH 112
#define WW 112
#define CIN 64
#define COUT 128
#define HOUT 110
#define WOUT 110
#define MTOT 387200
#define NWG 3025   // 387200 / 128
#define NXCD 8
#define XNE 25690112  // 32*112*112*64 elements of x

__device__ __forceinline__ unsigned short f2bf(float f) {
  unsigned int x = __float_as_uint(f);
  x += 0x7fffu + ((x >> 16) & 1u);
  return (unsigned short)(x >> 16);
}

// packed fp32 pair -> bf16 pair (v_cvt_pk_bf16_f32)
__device__ __forceinline__ unsigned int cvt2(float lo, float hi) {
  union { __hip_bfloat162 h; unsigned int u; } cv;
  cv.h = __float22bfloat162_rn(float2{lo, hi});
  return cv.u;
}

// async global->LDS, 16B per lane; LDS dest is wave-uniform base + lane*16
__device__ __forceinline__ void gload16(const unsigned short* g, unsigned short* l) {
  __builtin_amdgcn_global_load_lds(
      (const __attribute__((address_space(1))) void*)g,
      (__attribute__((address_space(3))) void*)l, 16, 0, 0);
}

// ---- prepass: x fp32 -> bf16 (NHWC layout preserved). 12544*256*8 == XNE exactly.
__global__ __launch_bounds__(256)
void cvt_x_kernel(const float* __restrict__ x, unsigned short* __restrict__ xb) {
  const int t = blockIdx.x * 256 + threadIdx.x;
  const f32x4* s = (const f32x4*)x + (size_t)t * 2;
  f32x4 a = s[0], b = s[1];
  u32x4 v;
  v[0] = cvt2(a[0], a[1]); v[1] = cvt2(a[2], a[3]);
  v[2] = cvt2(b[0], b[1]); v[3] = cvt2(b[2], b[3]);
  ((u32x4*)xb)[t] = v;
}

// ---- prepack kernels (3,3,64,128) fp32 HWIO -> swizzled LDS image:
// bt[tap*8192 + co*64 + e] = bf16(kern[(tap*64+ci)*128 + co]), ci=((e*2)^((co&7)<<4))>>1
__global__ void prepack_b_kernel(const float* __restrict__ kern,
                                 unsigned short* __restrict__ bt) {
  int idx = blockIdx.x * 256 + threadIdx.x;
  if (idx >= 9 * 8192) return;
  int tap = idx >> 13;
  int rem = idx & 8191;
  int co = rem >> 6;
  int e = rem & 63;
  int ci = ((e * 2) ^ ((co & 7) << 4)) >> 1;
  bt[idx] = f2bf(kern[(tap * 64 + ci) * COUT + co]);
}

// ---- main: m97-structure implicit GEMM. DMA staging, dbuf, 1 barrier/tap.
__global__ __launch_bounds__(512, 4)
void conv_dma_kernel(const unsigned short* __restrict__ xb,
                     const unsigned short* __restrict__ bt,
                     const float* __restrict__ bias,
                     float* __restrict__ out) {
  __shared__ __align__(16) unsigned short As[2][8192];
  __shared__ __align__(16) unsigned short Bs[2][8192];

  const int tid = threadIdx.x;
  const int lane = tid & 63;
  const int wid = tid >> 6;

  // bijective XCD-chunked remap (m204)
  const int bid = blockIdx.x;
  const int q = NWG / NXCD, r = NWG % NXCD;
  const int xcd = bid % NXCD, i8 = bid / NXCD;
  const int wg = (xcd < r ? xcd * (q + 1) : r * (q + 1) + (xcd - r) * q) + i8;
  const int m0 = wg * 128;

  // ---- staging precompute: wave w owns A/B image bytes [w*2048, w*2048+2048),
  // two DMA instructions (j=0,1). Lane's byte o = w*2048 + j*1024 + lane*16.
  // LDS image: row rr (pixel / cout), 128 B per row, chunk s holds global
  // chunk s^(rr&7)  -> pre-swizzled SOURCE, linear DEST (rule: both-sides).
  int aoff[2];
  const int obase = wid * 2048 + lane * 16;
#pragma unroll
  for (int j = 0; j < 2; ++j) {
    const int o = obase + j * 1024;
    const int rr = o >> 7;
    const int ss = (o >> 4) & 7;
    const int sp = ss ^ (rr & 7);
    const int m = m0 + rr;
    const int wo = m % WOUT;
    const int t1 = m / WOUT;
    const int ho = t1 % HOUT;
    const int bb = t1 / HOUT;
    aoff[j] = (((bb * HH) + ho) * WW + wo) * CIN + sp * 8;
  }
  const int ldsw0 = wid * 1024;        // wave-uniform LDS element base, j=0
  const int ldsw1 = wid * 1024 + 512;  // j=1
  const int blin0 = ldsw0 + lane * 8;  // per-lane B source (image is pre-swizzled)
  const int blin1 = ldsw1 + lane * 8;

  // ---- compute config: 8 waves = 4(m) x 2(n); wave tile 32x64 = 2x4 frags
  const int wm = wid >> 1;
  const int wn = wid & 1;
  const int l16 = lane & 15;
  const int lk = lane >> 4;
  const int swzR = (l16 & 7) << 4;

  const int aroff0 = (wm * 32 + 0 + l16) * 64;
  const int aroff1 = (wm * 32 + 16 + l16) * 64;
  const int broff0 = (wn * 64 + 0 + l16) * 64;
  const int broff1 = (wn * 64 + 16 + l16) * 64;
  const int broff2 = (wn * 64 + 32 + l16) * 64;
  const int broff3 = (wn * 64 + 48 + l16) * 64;

  f32x4 acc[2][4];
#pragma unroll
  for (int i = 0; i < 2; ++i)
#pragma unroll
    for (int j = 0; j < 4; ++j)
      acc[i][j] = (f32x4){0.f, 0.f, 0.f, 0.f};

  // ---- prologue: DMA tap 0 into buffer 0
  gload16(xb + aoff[0], &As[0][ldsw0]);
  gload16(xb + aoff[1], &As[0][ldsw1]);
  gload16(bt + blin0, &Bs[0][ldsw0]);
  gload16(bt + blin1, &Bs[0][ldsw1]);
  __syncthreads();  // implicit vmcnt(0) drain: buf0 staged

#pragma unroll
  for (int kk = 0; kk < 9; ++kk) {
    const int cur = kk & 1;
    const int nxt = cur ^ 1;

    // ---- issue tap kk+1 DMA into buf[nxt]; latency hides under compute
    if (kk < 8) {
      const int kn = kk + 1;
      const int kh = kn / 3;
      const int kw = kn - kh * 3;
      const int te = (kh * WW + kw) * CIN;
      const int tb = kn * 8192;
      gload16(xb + aoff[0] + te, &As[nxt][ldsw0]);
      gload16(xb + aoff[1] + te, &As[nxt][ldsw1]);
      gload16(bt + tb + blin0, &Bs[nxt][ldsw0]);
      gload16(bt + tb + blin1, &Bs[nxt][ldsw1]);
    }

    // ---- compute from buf[cur]: 2 k-steps of 32, 8 MFMA each (R5-proven)
    const unsigned short* Ac = As[cur];
    const unsigned short* Bc = Bs[cur];
#pragma unroll
    for (int ks = 0; ks < 2; ++ks) {
      const int cbs = ((ks * 64 + lk * 16) ^ swzR) >> 1;
      bf16x8 a0 = *(const bf16x8*)(Ac + aroff0 + cbs);
      bf16x8 a1 = *(const bf16x8*)(Ac + aroff1 + cbs);
      bf16x8 b0 = *(const bf16x8*)(Bc + broff0 + cbs);
      bf16x8 b1 = *(const bf16x8*)(Bc + broff1 + cbs);
      bf16x8 b2 = *(const bf16x8*)(Bc + broff2 + cbs);
      bf16x8 b3 = *(const bf16x8*)(Bc + broff3 + cbs);
      acc[0][0] = __builtin_amdgcn_mfma_f32_16x16x32_bf16(a0, b0, acc[0][0], 0, 0, 0);
      acc[0][1] = __builtin_amdgcn_mfma_f32_16x16x32_bf16(a0, b1, acc[0][1], 0, 0, 0);
      acc[0][2] = __builtin_amdgcn_mfma_f32_16x16x32_bf16(a0, b2, acc[0][2], 0, 0, 0);
      acc[0][3] = __builtin_amdgcn_mfma_f32_16x16x32_bf16(a0, b3, acc[0][3], 0, 0, 0);
      acc[1][0] = __builtin_amdgcn_mfma_f32_16x16x32_bf16(a1, b0, acc[1][0], 0, 0, 0);
      acc[1][1] = __builtin_amdgcn_mfma_f32_16x16x32_bf16(a1, b1, acc[1][1], 0, 0, 0);
      acc[1][2] = __builtin_amdgcn_mfma_f32_16x16x32_bf16(a1, b2, acc[1][2], 0, 0, 0);
      acc[1][3] = __builtin_amdgcn_mfma_f32_16x16x32_bf16(a1, b3, acc[1][3], 0, 0, 0);
    }

    __syncthreads();  // drains DMA (vmcnt) + reads; buf[nxt] ready, cur reusable
  }

  // ---- epilogue: bias + relu, C/D layout col=lane&15, row=(lane>>4)*4+reg
  const int ncol = wn * 64 + l16;
  const float bv0 = bias[ncol + 0];
  const float bv1 = bias[ncol + 16];
  const float bv2 = bias[ncol + 32];
  const float bv3 = bias[ncol + 48];
  const int mrow0 = m0 + wm * 32 + lk * 4;
#pragma unroll
  for (int mf = 0; mf < 2; ++mf) {
#pragma unroll
    for (int j = 0; j < 4; ++j) {
      const int row = mrow0 + mf * 16 + j;
      float* orow = out + (size_t)row * COUT + ncol;
      orow[0]  = fmaxf(acc[mf][0][j] + bv0, 0.f);
      orow[16] = fmaxf(acc[mf][1][j] + bv1, 0.f);
      orow[32] = fmaxf(acc[mf][2][j] + bv2, 0.f);
      orow[48] = fmaxf(acc[mf][3][j] + bv3, 0.f);
    }
  }
}

// ---- fallback (no workspace): R5's direct-staging kernel, known-correct.
__global__ __launch_bounds__(512)
void conv_fallback_kernel(const float* __restrict__ x,
                          const float* __restrict__ kern,
                          const float* __restrict__ bias,
                          float* __restrict__ out) {
  __shared__ __align__(16) unsigned short As[2][128 * 64];
  __shared__ __align__(16) unsigned short Bs[2][128 * 64];

  const int tid = threadIdx.x;
  const int m0 = blockIdx.x * 128;

  const int sr = tid >> 2;
  const int sc = tid & 3;
  const int m = m0 + sr;
  const int wo = m % WOUT;
  const int t1 = m / WOUT;
  const int ho = t1 % HOUT;
  const int b = t1 / HOUT;
  const float* xrow = x + (((b * HH) + ho) * WW + wo) * CIN + sc * 16;
  const int swzS = (sr & 7) << 4;
  const int awoff0 = sr * 64 + ((((sc * 32) + 0) ^ swzS) >> 1);
  const int awoff1 = sr * 64 + ((((sc * 32) + 16) ^ swzS) >> 1);

  const int bci = tid >> 3;
  const int bco = (tid & 7) * 16;

  const int lane = tid & 63;
  const int wid = tid >> 6;
  const int wm = wid >> 1;
  const int wn = wid & 1;
  const int l16 = lane & 15;
  const int lk = lane >> 4;
  const int swzR = (l16 & 7) << 4;

  const int aroff0 = (wm * 32 + 0 + l16) * 64;
  const int aroff1 = (wm * 32 + 16 + l16) * 64;
  const int broff0 = (wn * 64 + 0 + l16) * 64;
  const int broff1 = (wn * 64 + 16 + l16) * 64;
  const int broff2 = (wn * 64 + 32 + l16) * 64;
  const int broff3 = (wn * 64 + 48 + l16) * 64;

  f32x4 acc[2][4];
#pragma unroll
  for (int i = 0; i < 2; ++i)
#pragma unroll
    for (int j = 0; j < 4; ++j)
      acc[i][j] = (f32x4){0.f, 0.f, 0.f, 0.f};

  {
    f32x4 f0 = *(const f32x4*)(xrow + 0);
    f32x4 f1 = *(const f32x4*)(xrow + 4);
    f32x4 f2 = *(const f32x4*)(xrow + 8);
    f32x4 f3 = *(const f32x4*)(xrow + 12);
    u32x4 va, vb;
    va[0] = cvt2(f0[0], f0[1]); va[1] = cvt2(f0[2], f0[3]);
    va[2] = cvt2(f1[0], f1[1]); va[3] = cvt2(f1[2], f1[3]);
    vb[0] = cvt2(f2[0], f2[1]); vb[1] = cvt2(f2[2], f2[3]);
    vb[2] = cvt2(f3[0], f3[1]); vb[3] = cvt2(f3[2], f3[3]);
    *(u32x4*)(As[0] + awoff0) = va;
    *(u32x4*)(As[0] + awoff1) = vb;
    const float* kslab = kern + bci * COUT + bco;
    f32x4 g0 = *(const f32x4*)(kslab + 0);
    f32x4 g1 = *(const f32x4*)(kslab + 4);
    f32x4 g2 = *(const f32x4*)(kslab + 8);
    f32x4 g3 = *(const f32x4*)(kslab + 12);
#pragma unroll
    for (int j = 0; j < 4; ++j) {
      int c0 = bco + j;
      Bs[0][c0 * 64 + (((bci * 2) ^ ((c0 & 7) << 4)) >> 1)] = f2bf(g0[j]);
      int c1 = bco + 4 + j;
      Bs[0][c1 * 64 + (((bci * 2) ^ ((c1 & 7) << 4)) >> 1)] = f2bf(g1[j]);
      int c2 = bco + 8 + j;
      Bs[0][c2 * 64 + (((bci * 2) ^ ((c2 & 7) << 4)) >> 1)] = f2bf(g2[j]);
      int c3 = bco + 12 + j;
      Bs[0][c3 * 64 + (((bci * 2) ^ ((c3 & 7) << 4)) >> 1)] = f2bf(g3[j]);
    }
  }

#pragma unroll
  for (int kk = 0; kk < 9; ++kk) {
    const int cur = kk & 1;
    const int nxt = cur ^ 1;

    f32x4 g0, g1, g2, g3;
    f32x4 h0, h1, h2, h3;
    if (kk < 8) {
      const int kn = kk + 1;
      const int kh2 = kn / 3;
      const int kw2 = kn - kh2 * 3;
      const float* src = xrow + (kh2 * WW + kw2) * CIN;
      g0 = *(const f32x4*)(src + 0);
      g1 = *(const f32x4*)(src + 4);
      g2 = *(const f32x4*)(src + 8);
      g3 = *(const f32x4*)(src + 12);
      const float* kslab = kern + (kn * 64 + bci) * COUT + bco;
      h0 = *(const f32x4*)(kslab + 0);
      h1 = *(const f32x4*)(kslab + 4);
      h2 = *(const f32x4*)(kslab + 8);
      h3 = *(const f32x4*)(kslab + 12);
    }

    __syncthreads();

    const unsigned short* Ac = As[cur];
    const unsigned short* Bc = Bs[cur];
#pragma unroll
    for (int ks = 0; ks < 2; ++ks) {
      const int cbs = ((ks * 64 + lk * 16) ^ swzR) >> 1;
      bf16x8 a0 = *(const bf16x8*)(Ac + aroff0 + cbs);
      bf16x8 a1 = *(const bf16x8*)(Ac + aroff1 + cbs);
      bf16x8 b0 = *(const bf16x8*)(Bc + broff0 + cbs);
      bf16x8 b1 = *(const bf16x8*)(Bc + broff1 + cbs);
      bf16x8 b2 = *(const bf16x8*)(Bc + broff2 + cbs);
      bf16x8 b3 = *(const bf16x8*)(Bc + broff3 + cbs);
      acc[0][0] = __builtin_amdgcn_mfma_f32_16x16x32_bf16(a0, b0, acc[0][0], 0, 0, 0);
      acc[0][1] = __builtin_amdgcn_mfma_f32_16x16x32_bf16(a0, b1, acc[0][1], 0, 0, 0);
      acc[0][2] = __builtin_amdgcn_mfma_f32_16x16x32_bf16(a0, b2, acc[0][2], 0, 0, 0);
      acc[0][3] = __builtin_amdgcn_mfma_f32_16x16x32_bf16(a0, b3, acc[0][3], 0, 0, 0);
      acc[1][0] = __builtin_amdgcn_mfma_f32_16x16x32_bf16(a1, b0, acc[1][0], 0, 0, 0);
      acc[1][1] = __builtin_amdgcn_mfma_f32_16x16x32_bf16(a1, b1, acc[1][1], 0, 0, 0);
      acc[1][2] = __builtin_amdgcn_mfma_f32_16x16x32_bf16(a1, b2, acc[1][2], 0, 0, 0);
      acc[1][3] = __builtin_amdgcn_mfma_f32_16x16x32_bf16(a1, b3, acc[1][3], 0, 0, 0);
    }

    if (kk < 8) {
      u32x4 va, vb;
      va[0] = cvt2(g0[0], g0[1]); va[1] = cvt2(g0[2], g0[3]);
      va[2] = cvt2(g1[0], g1[1]); va[3] = cvt2(g1[2], g1[3]);
      vb[0] = cvt2(g2[0], g2[1]); vb[1] = cvt2(g2[2], g2[3]);
      vb[2] = cvt2(g3[0], g3[1]); vb[3] = cvt2(g3[2], g3[3]);
      *(u32x4*)(As[nxt] + awoff0) = va;
      *(u32x4*)(As[nxt] + awoff1) = vb;
#pragma unroll
      for (int j = 0; j < 4; ++j) {
        int c0 = bco + j;
        Bs[nxt][c0 * 64 + (((bci * 2) ^ ((c0 & 7) << 4)) >> 1)] = f2bf(h0[j]);
        int c1 = bco + 4 + j;
        Bs[nxt][c1 * 64 + (((bci * 2) ^ ((c1 & 7) << 4)) >> 1)] = f2bf(h1[j]);
        int c2 = bco + 8 + j;
        Bs[nxt][c2 * 64 + (((bci * 2) ^ ((c2 & 7) << 4)) >> 1)] = f2bf(h2[j]);
        int c3 = bco + 12 + j;
        Bs[nxt][c3 * 64 + (((bci * 2) ^ ((c3 & 7) << 4)) >> 1)] = f2bf(h3[j]);
      }
    }
  }

  const int ncol = wn * 64 + l16;
  const float bv0 = bias[ncol + 0];
  const float bv1 = bias[ncol + 16];
  const float bv2 = bias[ncol + 32];
  const float bv3 = bias[ncol + 48];
  const int mrow0 = m0 + wm * 32 + lk * 4;
#pragma unroll
  for (int mf = 0; mf < 2; ++mf) {
#pragma unroll
    for (int j = 0; j < 4; ++j) {
      const int row = mrow0 + mf * 16 + j;
      float* orow = out + (size_t)row * COUT + ncol;
      orow[0]  = fmaxf(acc[mf][0][j] + bv0, 0.f);
      orow[16] = fmaxf(acc[mf][1][j] + bv1, 0.f);
      orow[32] = fmaxf(acc[mf][2][j] + bv2, 0.f);
      orow[48] = fmaxf(acc[mf][3][j] + bv3, 0.f);
    }
  }
}

extern "C" void kernel_launch(void* const* d_in, const int* in_sizes, int n_in,
                              void* d_out, int out_size, void* d_ws, size_t ws_size,
                              hipStream_t stream) {
  const float* x = (const float*)d_in[0];
  const float* kern = (const float*)d_in[1];
  const float* bias = (const float*)d_in[2];
  float* out = (float*)d_out;

  const size_t xb_bytes = (size_t)XNE * 2;
  const size_t bt_bytes = 9 * 8192 * 2;
  if (d_ws != nullptr && ws_size >= xb_bytes + bt_bytes) {
    unsigned short* xb = (unsigned short*)d_ws;
    unsigned short* bt = xb + XNE;
    cvt_x_kernel<<<12544, 256, 0, stream>>>(x, xb);
    prepack_b_kernel<<<288, 256, 0, stream>>>(kern, bt);
    conv_dma_kernel<<<NWG, 512, 0, stream>>>(xb, bt, bias, out);
  } else {
    conv_fallback_kernel<<<NWG, 512, 0, stream>>>(x, kern, bias, out);
  }
}